// Round 2
// baseline (825.611 us; speedup 1.0000x reference)
//
#include <hip/hip_runtime.h>
#include <hip/hip_bf16.h>

typedef unsigned short u16;
typedef __attribute__((ext_vector_type(8))) short short8;
typedef __attribute__((ext_vector_type(4))) float floatx4;

#define NU 16384
#define DIM 256
#define HW 64     // half window
#define TW 128    // 2*W

__device__ __forceinline__ u16 bftrunc(float v) {
  return (u16)(__float_as_uint(v) >> 16);
}
__device__ __forceinline__ float bfup(u16 u) {
  return __uint_as_float(((unsigned int)u) << 16);
}

// ---------------------------------------------------------------------------
// Kernel 1: supports = x @ W_r for r in {att, pred, suc, same, diff}.
// fp32 in/out; split-bf16 (hi+lo) 3-MFMA decomposition for ~fp32 accuracy.
// C tile 64x64 per block, 4 waves each compute 16 rows x 64 cols.
// grid = (NU/64, 20): blockIdx.y>>2 selects matrix, &3 selects 64-col strip.
// ---------------------------------------------------------------------------
__global__ __launch_bounds__(256) void gemm5(
    const float* __restrict__ x,
    const float* __restrict__ w0, const float* __restrict__ w1,
    const float* __restrict__ w2, const float* __restrict__ w3,
    const float* __restrict__ w4,
    float* __restrict__ sup)
{
  __shared__ __align__(16) u16 Ah[64][32], Al[64][32];   // [m][k]
  __shared__ __align__(16) u16 Bh[64][32], Bl[64][32];   // [n][k] (transposed)

  const int t    = threadIdx.x;
  const int mat  = blockIdx.y >> 2;
  const int col0 = (blockIdx.y & 3) * 64;
  const int row0 = blockIdx.x * 64;
  const float* Wm = (mat == 0) ? w0 : (mat == 1) ? w1 : (mat == 2) ? w2
                  : (mat == 3) ? w3 : w4;

  const int l  = t & 63;
  const int wv = t >> 6;
  const int ar = t >> 2,  ac = (t & 3) * 8;   // A staging: row 0..63, 8-k chunk
  const int bk = t >> 3,  bc = (t & 7) * 8;   // B staging: k 0..31, 8-col chunk

  floatx4 acc[4];
#pragma unroll
  for (int f = 0; f < 4; ++f) acc[f] = (floatx4){0.f, 0.f, 0.f, 0.f};

  const int am = wv * 16 + (l & 15);          // A fragment row
  const int ks = (l >> 4) * 8;                // fragment k base

  for (int k0 = 0; k0 < DIM; k0 += 32) {
    // --- A tile: 8 fp32 per thread -> hi/lo bf16 ---
    {
      const float* ap = x + (size_t)(row0 + ar) * DIM + k0 + ac;
      float4 v0 = *(const float4*)(ap);
      float4 v1 = *(const float4*)(ap + 4);
      float av[8] = {v0.x, v0.y, v0.z, v0.w, v1.x, v1.y, v1.z, v1.w};
      u16 h8[8], l8[8];
#pragma unroll
      for (int u = 0; u < 8; ++u) {
        h8[u] = bftrunc(av[u]);
        l8[u] = bftrunc(av[u] - bfup(h8[u]));
      }
      *(uint4*)(&Ah[ar][ac]) = *(const uint4*)h8;
      *(uint4*)(&Al[ar][ac]) = *(const uint4*)l8;
    }
    // --- B tile: 8 fp32 per thread, transposed store ---
    {
      const float* bp = Wm + (size_t)(k0 + bk) * DIM + col0 + bc;
      float4 v0 = *(const float4*)(bp);
      float4 v1 = *(const float4*)(bp + 4);
      float bvv[8] = {v0.x, v0.y, v0.z, v0.w, v1.x, v1.y, v1.z, v1.w};
#pragma unroll
      for (int u = 0; u < 8; ++u) {
        u16 hh = bftrunc(bvv[u]);
        Bh[bc + u][bk] = hh;
        Bl[bc + u][bk] = bftrunc(bvv[u] - bfup(hh));
      }
    }
    __syncthreads();

    short8 ahi = *(const short8*)(&Ah[am][ks]);
    short8 alo = *(const short8*)(&Al[am][ks]);
#pragma unroll
    for (int f = 0; f < 4; ++f) {
      short8 bhi = *(const short8*)(&Bh[f * 16 + (l & 15)][ks]);
      short8 blo = *(const short8*)(&Bl[f * 16 + (l & 15)][ks]);
      acc[f] = __builtin_amdgcn_mfma_f32_16x16x32_bf16(ahi, bhi, acc[f], 0, 0, 0);
      acc[f] = __builtin_amdgcn_mfma_f32_16x16x32_bf16(ahi, blo, acc[f], 0, 0, 0);
      acc[f] = __builtin_amdgcn_mfma_f32_16x16x32_bf16(alo, bhi, acc[f], 0, 0, 0);
    }
    __syncthreads();
  }

  float* outp = sup + (size_t)mat * NU * DIM;
  const int crow = row0 + wv * 16 + (l >> 4) * 4;   // C/D: col=lane&15, row=quad*4+reg
#pragma unroll
  for (int f = 0; f < 4; ++f) {
    int c = col0 + f * 16 + (l & 15);
#pragma unroll
    for (int r = 0; r < 4; ++r)
      outp[(size_t)(crow + r) * DIM + c] = acc[f][r];
  }
}

// ---------------------------------------------------------------------------
// Kernel 2: per-utterance attention + relation aggregation + log_softmax.
// One block (256 threads) per utterance. All fp32.
// ---------------------------------------------------------------------------
__global__ __launch_bounds__(256) void attn_agg(
    const float* __restrict__ x, const int* __restrict__ spk,
    const float* __restrict__ sup, float* __restrict__ out)
{
  __shared__ float ylds[DIM];
  __shared__ float part[256];
  __shared__ float rawl[TW];
  __shared__ float attn[TW];
  __shared__ int   validv[TW];
  __shared__ int   samev[TW];
  __shared__ float red[4];
  __shared__ int   myspk_s;

  const int i = blockIdx.x;
  const int t = threadIdx.x;

  const float* y_att  = sup;
  const float* s_pred = sup + (size_t)1 * NU * DIM;
  const float* s_suc  = sup + (size_t)2 * NU * DIM;
  const float* s_same = sup + (size_t)3 * NU * DIM;
  const float* s_diff = sup + (size_t)4 * NU * DIM;

  ylds[t] = y_att[(size_t)i * DIM + t];
  if (t == 0) myspk_s = spk[i];
  __syncthreads();

  // --- raw attention logits: 2 threads per window slot, 128 dims each ---
  const int w    = t & (TW - 1);
  const int half = t >> 7;
  const int j    = i + w - HW;
  const bool valid = (j >= 0) && (j < NU);
  float p = 0.f;
  if (valid) {
    const float4* xr = (const float4*)(x + (size_t)j * DIM + half * 128);
    const float*  yb = ylds + half * 128;
#pragma unroll
    for (int u = 0; u < 32; ++u) {
      float4 v = xr[u];
      p += v.x * yb[4*u] + v.y * yb[4*u+1] + v.z * yb[4*u+2] + v.w * yb[4*u+3];
    }
  }
  part[t] = p;
  if (half == 0) {
    validv[w] = valid ? 1 : 0;
    samev[w]  = (valid && (spk[j] == myspk_s)) ? 1 : 0;
  }
  __syncthreads();
  // invalid slots carry raw=0 and ARE part of the softmax denominator (ref
  // zero-pads the windows), but are excluded from aggregation by the masks.
  if (t < TW) rawl[t] = validv[t] ? (part[t] + part[t + 128]) : 0.f;
  __syncthreads();

  // --- softmax over all 128 slots ---
  float v = (t < TW) ? rawl[t] : -3.4e38f;
#pragma unroll
  for (int o = 32; o > 0; o >>= 1) v = fmaxf(v, __shfl_xor(v, o));
  if ((t & 63) == 0) red[t >> 6] = v;
  __syncthreads();
  float m = fmaxf(fmaxf(red[0], red[1]), fmaxf(red[2], red[3]));
  __syncthreads();
  float e = (t < TW) ? __expf(rawl[t] - m) : 0.f;
  float sv = e;
#pragma unroll
  for (int o = 32; o > 0; o >>= 1) sv += __shfl_xor(sv, o);
  if ((t & 63) == 0) red[t >> 6] = sv;
  __syncthreads();
  float ssum = red[0] + red[1] + red[2] + red[3];
  __syncthreads();
  if (t < TW) attn[t] = e / ssum;
  __syncthreads();

  // --- aggregation: thread t owns dim d=t ---
  float h = 0.f;
  for (int ww = 0; ww < TW; ++ww) {
    if (!validv[ww]) continue;               // block-uniform branch
    const int jj = i + ww - HW;
    const float* po = (ww >= HW) ? s_pred : s_suc;
    const float* sd = samev[ww] ? s_same : s_diff;
    const size_t off = (size_t)jj * DIM + t;
    h += attn[ww] * (po[off] + sd[off]);
  }

  // --- log_softmax over 256 dims ---
  float hv = h;
#pragma unroll
  for (int o = 32; o > 0; o >>= 1) hv = fmaxf(hv, __shfl_xor(hv, o));
  if ((t & 63) == 0) red[t >> 6] = hv;
  __syncthreads();
  float hm = fmaxf(fmaxf(red[0], red[1]), fmaxf(red[2], red[3]));
  __syncthreads();
  float ex = __expf(h - hm);
  float sx = ex;
#pragma unroll
  for (int o = 32; o > 0; o >>= 1) sx += __shfl_xor(sx, o);
  if ((t & 63) == 0) red[t >> 6] = sx;
  __syncthreads();
  float lse = logf(red[0] + red[1] + red[2] + red[3]);
  out[(size_t)i * DIM + t] = h - hm - lse;
}

extern "C" void kernel_launch(void* const* d_in, const int* in_sizes, int n_in,
                              void* d_out, int out_size, void* d_ws, size_t ws_size,
                              hipStream_t stream) {
  const float* x   = (const float*)d_in[0];
  const int*   spk = (const int*)d_in[1];
  const float* wat = (const float*)d_in[2];
  const float* wpr = (const float*)d_in[3];
  const float* wsu = (const float*)d_in[4];
  const float* wsm = (const float*)d_in[5];
  const float* wdf = (const float*)d_in[6];
  float* out = (float*)d_out;
  float* sup = (float*)d_ws;   // 5 * NU * DIM fp32 = 80 MB scratch

  dim3 g1(NU / 64, 20);
  hipLaunchKernelGGL(gemm5, g1, dim3(256), 0, stream,
                     x, wat, wpr, wsu, wsm, wdf, sup);
  hipLaunchKernelGGL(attn_agg, dim3(NU), dim3(256), 0, stream,
                     x, spk, sup, out);
}

// Round 3
// 204.965 us; speedup vs baseline: 4.0281x; 4.0281x over previous
//
#include <hip/hip_runtime.h>
#include <hip/hip_bf16.h>

typedef unsigned short u16;
typedef unsigned int u32;
typedef __attribute__((ext_vector_type(8))) short short8;
typedef __attribute__((ext_vector_type(4))) float floatx4;

#define NU 16384
#define DIM 256
#define LDW 40   // padded LDS row stride (u16) for bf16 fragment tiles

__device__ __forceinline__ u16 bfh(float v) {            // truncate to bf16
  return (u16)(__float_as_uint(v) >> 16);
}
__device__ __forceinline__ float bup(u16 u) {
  return __uint_as_float(((u32)u) << 16);
}
__device__ __forceinline__ u16 bfrn(float v) {           // round-to-nearest-even
  u32 u = __float_as_uint(v);
  return (u16)((u + 0x7fffu + ((u >> 16) & 1u)) >> 16);
}
__device__ __forceinline__ void splitbf4(float4 v, ushort4& h, ushort4& l) {
  float a[4] = {v.x, v.y, v.z, v.w};
  u16 hh[4], ll[4];
#pragma unroll
  for (int q = 0; q < 4; ++q) {
    hh[q] = bfh(a[q]);
    ll[q] = bfh(a[q] - bup(hh[q]));
  }
  h = make_ushort4(hh[0], hh[1], hh[2], hh[3]);
  l = make_ushort4(ll[0], ll[1], ll[2], ll[3]);
}

// ---------------------------------------------------------------------------
// Kernel 1: sup[0]=x@W_att, sup[1]=x@(W_pred-W_suc), sup[2]=x@(W_same-W_diff),
//           sup[3]=x@(W_suc+W_diff).  Split-bf16 3-MFMA (~fp32 accuracy).
// grid = (NU/64, 16): blockIdx.y>>2 = matrix, &3 = 64-col strip.
// ---------------------------------------------------------------------------
__global__ __launch_bounds__(256) void gemm4(
    const float* __restrict__ x,
    const float* __restrict__ wat, const float* __restrict__ wpr,
    const float* __restrict__ wsu, const float* __restrict__ wsm,
    const float* __restrict__ wdf,
    float* __restrict__ sup)
{
  __shared__ __align__(16) u16 Ah[64][32], Al[64][32];   // [m][k]
  __shared__ __align__(16) u16 Bh[64][32], Bl[64][32];   // [n][k] (transposed)

  const int t    = threadIdx.x;
  const int mat  = blockIdx.y >> 2;
  const int col0 = (blockIdx.y & 3) * 64;
  const int row0 = blockIdx.x * 64;
  const float* Wa = (mat == 0) ? wat : (mat == 1) ? wpr : (mat == 2) ? wsm : wsu;
  const float* Wb = (mat == 0) ? wat : (mat == 1) ? wsu : (mat == 2) ? wdf : wdf;
  const float c1  = (mat == 0) ? 0.f : (mat == 3) ? 1.f : -1.f;

  const int l  = t & 63;
  const int wv = t >> 6;
  const int ar = t >> 2,  ac = (t & 3) * 8;
  const int bk = t >> 3,  bc = (t & 7) * 8;

  floatx4 acc[4];
#pragma unroll
  for (int f = 0; f < 4; ++f) acc[f] = (floatx4){0.f, 0.f, 0.f, 0.f};

  const int am = wv * 16 + (l & 15);
  const int ks = (l >> 4) * 8;

  for (int k0 = 0; k0 < DIM; k0 += 32) {
    {
      const float* ap = x + (size_t)(row0 + ar) * DIM + k0 + ac;
      float4 v0 = *(const float4*)(ap);
      float4 v1 = *(const float4*)(ap + 4);
      ushort4 h0, l0, h1, l1;
      splitbf4(v0, h0, l0);
      splitbf4(v1, h1, l1);
      *(ushort4*)(&Ah[ar][ac])     = h0;
      *(ushort4*)(&Ah[ar][ac + 4]) = h1;
      *(ushort4*)(&Al[ar][ac])     = l0;
      *(ushort4*)(&Al[ar][ac + 4]) = l1;
    }
    {
      const float* bpA = Wa + (size_t)(k0 + bk) * DIM + col0 + bc;
      const float* bpB = Wb + (size_t)(k0 + bk) * DIM + col0 + bc;
      float4 a0 = *(const float4*)(bpA);
      float4 a1 = *(const float4*)(bpA + 4);
      float4 b0 = *(const float4*)(bpB);
      float4 b1 = *(const float4*)(bpB + 4);
      float bvv[8] = {a0.x + c1 * b0.x, a0.y + c1 * b0.y,
                      a0.z + c1 * b0.z, a0.w + c1 * b0.w,
                      a1.x + c1 * b1.x, a1.y + c1 * b1.y,
                      a1.z + c1 * b1.z, a1.w + c1 * b1.w};
#pragma unroll
      for (int u = 0; u < 8; ++u) {
        u16 hh = bfh(bvv[u]);
        Bh[bc + u][bk] = hh;
        Bl[bc + u][bk] = bfh(bvv[u] - bup(hh));
      }
    }
    __syncthreads();

    short8 ahi = *(const short8*)(&Ah[am][ks]);
    short8 alo = *(const short8*)(&Al[am][ks]);
#pragma unroll
    for (int f = 0; f < 4; ++f) {
      short8 bhi = *(const short8*)(&Bh[f * 16 + (l & 15)][ks]);
      short8 blo = *(const short8*)(&Bl[f * 16 + (l & 15)][ks]);
      acc[f] = __builtin_amdgcn_mfma_f32_16x16x32_bf16(ahi, bhi, acc[f], 0, 0, 0);
      acc[f] = __builtin_amdgcn_mfma_f32_16x16x32_bf16(ahi, blo, acc[f], 0, 0, 0);
      acc[f] = __builtin_amdgcn_mfma_f32_16x16x32_bf16(alo, bhi, acc[f], 0, 0, 0);
    }
    __syncthreads();
  }

  float* outp = sup + (size_t)mat * NU * DIM;
  const int crow = row0 + wv * 16 + (l >> 4) * 4;
#pragma unroll
  for (int f = 0; f < 4; ++f) {
    int c = col0 + f * 16 + (l & 15);
#pragma unroll
    for (int r = 0; r < 4; ++r)
      outp[(size_t)(crow + r) * DIM + c] = acc[f][r];
  }
}

// ---------------------------------------------------------------------------
// Kernel 2: fused banded attention + relation aggregation + log_softmax.
// One block = 64 consecutive utterances, window J=192 rows. 512 threads.
// Phase 1: P = Y @ Xw^T (split-bf16, 3 MFMA).  Phase S: softmax in LDS.
// Phase 2: H = A_pred@S1 + A_same@S2 + A_full@S3 (bf16 MFMA, K=192 by 32).
// ---------------------------------------------------------------------------
__global__ __launch_bounds__(512, 2) void fused_attn(
    const float* __restrict__ x, const int* __restrict__ spk,
    const float* __restrict__ sup, float* __restrict__ out)
{
  __shared__ float Plds[64][196];                 // P then attn (fp32)
  __shared__ __align__(16) u16 stg[38400];        // staging union (76.8 KB)
  __shared__ int spkw[192];
  __shared__ float pmax[64][8], psum[64][8], gmaxs[64], glse[64];

  const int t    = threadIdx.x;
  const int w    = t >> 6;
  const int ln   = t & 15;
  const int quad = (t & 63) >> 4;
  const int q8   = quad * 8;
  const int i0   = blockIdx.x * 64;

  const float* yatt = sup;

  if (t < 192) {
    int j = i0 + t - 64;
    spkw[t] = spk[min(max(j, 0), NU - 1)];
  }

  // ---------------- Phase 1: logits GEMM ----------------
  u16* Xh = stg;                       // [192][LDW]
  u16* Xl = stg + 192 * LDW;
  u16* Yh = stg + 2 * 192 * LDW;       // [64][LDW]
  u16* Yl = Yh + 64 * LDW;

  floatx4 accP[6];
#pragma unroll
  for (int cc = 0; cc < 6; ++cc) accP[cc] = (floatx4){0.f, 0.f, 0.f, 0.f};
  const int m0  = (w >> 1) * 16;
  const int ct0 = (w & 1) * 6;

  for (int kd = 0; kd < DIM; kd += 32) {
#pragma unroll
    for (int qq = 0; qq < 3; ++qq) {          // X window: 192 rows
      int p = t + 512 * qq;
      int row = p >> 3;
      int c4  = (p & 7) * 4;
      int j  = i0 + row - 64;
      int jc = min(max(j, 0), NU - 1);
      float4 v = *(const float4*)(x + (size_t)jc * DIM + kd + c4);
      ushort4 hv, lv;
      splitbf4(v, hv, lv);
      *(ushort4*)(&Xh[row * LDW + c4]) = hv;
      *(ushort4*)(&Xl[row * LDW + c4]) = lv;
    }
    {                                          // Y: 64 rows
      int row = t >> 3;
      int c4  = (t & 7) * 4;
      float4 v = *(const float4*)(yatt + (size_t)(i0 + row) * DIM + kd + c4);
      ushort4 hv, lv;
      splitbf4(v, hv, lv);
      *(ushort4*)(&Yh[row * LDW + c4]) = hv;
      *(ushort4*)(&Yl[row * LDW + c4]) = lv;
    }
    __syncthreads();

    short8 ah = *(const short8*)(&Yh[(m0 + ln) * LDW + q8]);
    short8 al = *(const short8*)(&Yl[(m0 + ln) * LDW + q8]);
#pragma unroll
    for (int cc = 0; cc < 6; ++cc) {
      short8 bh = *(const short8*)(&Xh[((ct0 + cc) * 16 + ln) * LDW + q8]);
      short8 bl = *(const short8*)(&Xl[((ct0 + cc) * 16 + ln) * LDW + q8]);
      accP[cc] = __builtin_amdgcn_mfma_f32_16x16x32_bf16(ah, bh, accP[cc], 0, 0, 0);
      accP[cc] = __builtin_amdgcn_mfma_f32_16x16x32_bf16(ah, bl, accP[cc], 0, 0, 0);
      accP[cc] = __builtin_amdgcn_mfma_f32_16x16x32_bf16(al, bh, accP[cc], 0, 0, 0);
    }
    __syncthreads();
  }
#pragma unroll
  for (int cc = 0; cc < 6; ++cc)
#pragma unroll
    for (int r = 0; r < 4; ++r)
      Plds[m0 + quad * 4 + r][(ct0 + cc) * 16 + ln] = accP[cc][r];
  __syncthreads();

  // ---------------- Softmax over each row's 128-slot band ----------------
  {
    int row = t >> 3, s = t & 7;
    float vals[16];
    float mx = -3.4e38f;
#pragma unroll
    for (int q = 0; q < 16; ++q) {
      int c = row + s * 16 + q;
      int j = i0 + c - 64;
      float pv = ((j >= 0) && (j < NU)) ? Plds[row][c] : 0.f;
      vals[q] = pv;
      mx = fmaxf(mx, pv);
    }
#pragma unroll
    for (int o = 1; o < 8; o <<= 1) mx = fmaxf(mx, __shfl_xor(mx, o));
    float sm = 0.f;
#pragma unroll
    for (int q = 0; q < 16; ++q) { vals[q] = __expf(vals[q] - mx); sm += vals[q]; }
#pragma unroll
    for (int o = 1; o < 8; o <<= 1) sm += __shfl_xor(sm, o);
    float inv = 1.f / sm;
#pragma unroll
    for (int q = 0; q < 16; ++q) {
      int c = row + s * 16 + q;
      int j = i0 + c - 64;
      Plds[row][c] = ((j >= 0) && (j < NU)) ? vals[q] * inv : 0.f;
    }
#pragma unroll
    for (int q = 0; q < 8; ++q) {              // zero out-of-band slots
      int c2 = row + 128 + s * 8 + q;
      if (c2 >= 192) c2 -= 192;
      Plds[row][c2] = 0.f;
    }
  }
  __syncthreads();

  // ---------------- Phase 2: aggregation GEMMs ----------------
  u16* Sl = stg;                         // [3][256][LDW] transposed supports
  u16* Ac = stg + 3 * 256 * LDW;         // [3][64][LDW] masked attn
  const int n0 = w * 32;

  floatx4 acc2[4][2];
#pragma unroll
  for (int m = 0; m < 4; ++m)
#pragma unroll
    for (int n2 = 0; n2 < 2; ++n2) acc2[m][n2] = (floatx4){0.f, 0.f, 0.f, 0.f};

  for (int kj = 0; kj < 192; kj += 32) {
    const int jbase = i0 - 64 + kj;
    // stage S chunks transposed: Sl[r][d][jj] = bf16(S_r[jbase+jj][d])
#pragma unroll
    for (int qq = 0; qq < 6; ++qq) {
      int p   = t + 512 * qq;
      int r   = p >> 10;
      int rem = p & 1023;
      int jp  = rem & 15;               // lane-fast: conflict-free LDS writes
      int d0  = (rem >> 4) * 4;
      const float* Sg = sup + (size_t)(r + 1) * NU * DIM;
      int j1 = jbase + 2 * jp, j2 = j1 + 1;
      int j1c = min(max(j1, 0), NU - 1), j2c = min(max(j2, 0), NU - 1);
      float4 v1 = *(const float4*)(Sg + (size_t)j1c * DIM + d0);
      float4 v2 = *(const float4*)(Sg + (size_t)j2c * DIM + d0);
      float a1[4] = {v1.x, v1.y, v1.z, v1.w};
      float a2[4] = {v2.x, v2.y, v2.z, v2.w};
#pragma unroll
      for (int q4 = 0; q4 < 4; ++q4) {
        u32 pk = (u32)bfrn(a1[q4]) | ((u32)bfrn(a2[q4]) << 16);
        *(u32*)(&Sl[r * 256 * LDW + (d0 + q4) * LDW + 2 * jp]) = pk;
      }
    }
    // build masked A chunks: Ac[0]=pred, Ac[1]=same, Ac[2]=full
    {
      int row = t >> 3, cg = t & 7;
      int cb = kj + cg * 4;
      float4 av = *(const float4*)(&Plds[row][cb]);
      float aa[4] = {av.x, av.y, av.z, av.w};
      int sr = spkw[row + 64];
      u16 b0[4], b1[4], b2[4];
#pragma unroll
      for (int q = 0; q < 4; ++q) {
        int c = cb + q;
        u16 ab = bfrn(aa[q]);
        b0[q] = (c - row >= 64) ? ab : (u16)0;       // pred: offset >= 0
        b1[q] = (spkw[c] == sr) ? ab : (u16)0;       // same speaker
        b2[q] = ab;                                  // full band
      }
      *(ushort4*)(&Ac[0 * 64 * LDW + row * LDW + cg * 4]) = make_ushort4(b0[0], b0[1], b0[2], b0[3]);
      *(ushort4*)(&Ac[1 * 64 * LDW + row * LDW + cg * 4]) = make_ushort4(b1[0], b1[1], b1[2], b1[3]);
      *(ushort4*)(&Ac[2 * 64 * LDW + row * LDW + cg * 4]) = make_ushort4(b2[0], b2[1], b2[2], b2[3]);
    }
    __syncthreads();

    short8 af[3][4], bfr[3][2];
#pragma unroll
    for (int r = 0; r < 3; ++r) {
#pragma unroll
      for (int m = 0; m < 4; ++m)
        af[r][m] = *(const short8*)(&Ac[r * 64 * LDW + (m * 16 + ln) * LDW + q8]);
#pragma unroll
      for (int n2 = 0; n2 < 2; ++n2)
        bfr[r][n2] = *(const short8*)(&Sl[r * 256 * LDW + (n0 + n2 * 16 + ln) * LDW + q8]);
    }
#pragma unroll
    for (int r = 0; r < 3; ++r)
#pragma unroll
      for (int m = 0; m < 4; ++m)
#pragma unroll
        for (int n2 = 0; n2 < 2; ++n2)
          acc2[m][n2] = __builtin_amdgcn_mfma_f32_16x16x32_bf16(
              af[r][m], bfr[r][n2], acc2[m][n2], 0, 0, 0);
    __syncthreads();
  }

  // ---------------- log_softmax over 256 dims (cross-wave) ----------------
#pragma unroll
  for (int m = 0; m < 4; ++m)
#pragma unroll
    for (int r = 0; r < 4; ++r) {
      float v = fmaxf(acc2[m][0][r], acc2[m][1][r]);
#pragma unroll
      for (int o = 1; o < 16; o <<= 1) v = fmaxf(v, __shfl_xor(v, o));
      if (ln == 0) pmax[m * 16 + quad * 4 + r][w] = v;
    }
  __syncthreads();
  if (t < 64) {
    float g = pmax[t][0];
#pragma unroll
    for (int ww = 1; ww < 8; ++ww) g = fmaxf(g, pmax[t][ww]);
    gmaxs[t] = g;
  }
  __syncthreads();
#pragma unroll
  for (int m = 0; m < 4; ++m)
#pragma unroll
    for (int r = 0; r < 4; ++r) {
      float g = gmaxs[m * 16 + quad * 4 + r];
      float e = __expf(acc2[m][0][r] - g) + __expf(acc2[m][1][r] - g);
#pragma unroll
      for (int o = 1; o < 16; o <<= 1) e += __shfl_xor(e, o);
      if (ln == 0) psum[m * 16 + quad * 4 + r][w] = e;
    }
  __syncthreads();
  if (t < 64) {
    float s = psum[t][0];
#pragma unroll
    for (int ww = 1; ww < 8; ++ww) s += psum[t][ww];
    glse[t] = gmaxs[t] + logf(s);
  }
  __syncthreads();

#pragma unroll
  for (int m = 0; m < 4; ++m) {
    int rl0 = m * 16 + quad * 4;
#pragma unroll
    for (int r = 0; r < 4; ++r) {
      float l = glse[rl0 + r];
      size_t rowg = (size_t)(i0 + rl0 + r) * DIM;
      out[rowg + n0 + ln]      = acc2[m][0][r] - l;
      out[rowg + n0 + 16 + ln] = acc2[m][1][r] - l;
    }
  }
}

extern "C" void kernel_launch(void* const* d_in, const int* in_sizes, int n_in,
                              void* d_out, int out_size, void* d_ws, size_t ws_size,
                              hipStream_t stream) {
  const float* x   = (const float*)d_in[0];
  const int*   spk = (const int*)d_in[1];
  const float* wat = (const float*)d_in[2];
  const float* wpr = (const float*)d_in[3];
  const float* wsu = (const float*)d_in[4];
  const float* wsm = (const float*)d_in[5];
  const float* wdf = (const float*)d_in[6];
  float* out = (float*)d_out;
  float* sup = (float*)d_ws;   // 4 * NU * DIM fp32 = 64 MB scratch

  dim3 g1(NU / 64, 16);
  hipLaunchKernelGGL(gemm4, g1, dim3(256), 0, stream,
                     x, wat, wpr, wsu, wsm, wdf, sup);
  hipLaunchKernelGGL(fused_attn, dim3(NU / 64), dim3(512), 0, stream,
                     x, spk, sup, out);
}

// Round 4
// 169.037 us; speedup vs baseline: 4.8842x; 1.2125x over previous
//
#include <hip/hip_runtime.h>
#include <hip/hip_bf16.h>

typedef unsigned short u16;
typedef unsigned int u32;
typedef __attribute__((ext_vector_type(8))) short short8;
typedef __attribute__((ext_vector_type(4))) float floatx4;

#define NU 16384
#define DIM 256

// d_ws layout, offsets in u16 units (total 67.96 MB)
#define XHo 0u
#define XLo 4194304u
#define XRo 8388608u
#define YHo 12582912u
#define YLo 16777216u
#define ST0 20971520u
#define STROW 16512u          // 16384 + 2*64 guard cols
#define STMAT 4227072u        // 256 * STROW
#define WH0o 33652736u
#define WL0o 33718272u
#define WRo  33783808u        // 3 mats x 65536

__device__ __forceinline__ u16 bfh(float v) {            // truncate to bf16
  return (u16)(__float_as_uint(v) >> 16);
}
__device__ __forceinline__ float bup(u16 u) {
  return __uint_as_float(((u32)u) << 16);
}
__device__ __forceinline__ u16 bfrn(float v) {           // round-nearest-even
  u32 u = __float_as_uint(v);
  return (u16)((u + 0x7fffu + ((u >> 16) & 1u)) >> 16);
}

// ---------------------------------------------------------------------------
// xprep: xh/xl (split) + xr (rounded) bf16 copies of x.
// ---------------------------------------------------------------------------
__global__ __launch_bounds__(256) void xprep(const float* __restrict__ x,
                                             u16* __restrict__ ws) {
  int idx = (blockIdx.x * 256 + threadIdx.x) * 4;
  float4 v = *(const float4*)(x + idx);
  float a[4] = {v.x, v.y, v.z, v.w};
  u16 h[4], l[4], r[4];
#pragma unroll
  for (int q = 0; q < 4; ++q) {
    h[q] = bfh(a[q]);
    l[q] = bfh(a[q] - bup(h[q]));
    r[q] = bfrn(a[q]);
  }
  *(ushort4*)(ws + XHo + idx) = make_ushort4(h[0], h[1], h[2], h[3]);
  *(ushort4*)(ws + XLo + idx) = make_ushort4(l[0], l[1], l[2], l[3]);
  *(ushort4*)(ws + XRo + idx) = make_ushort4(r[0], r[1], r[2], r[3]);
}

// ---------------------------------------------------------------------------
// wprep: combined weights in [s][n][k] LDS-tile image order.
// mat0 = W_att (hi+lo split); mat1 = Wp-Ws, mat2 = Wsm-Wdf, mat3 = Ws+Wdf (RNE).
// ---------------------------------------------------------------------------
__global__ __launch_bounds__(256) void wprep(
    const float* __restrict__ wat, const float* __restrict__ wpr,
    const float* __restrict__ wsu, const float* __restrict__ wsm,
    const float* __restrict__ wdf, u16* __restrict__ ws) {
  const int s = blockIdx.x, mat = blockIdx.y, n = threadIdx.x;
  const float* Wa = (mat == 0) ? wat : (mat == 1) ? wpr : (mat == 2) ? wsm : wsu;
  const float* Wb = (mat == 0) ? wat : (mat == 1) ? wsu : (mat == 2) ? wdf : wdf;
  const float c1  = (mat == 0) ? 0.f : (mat == 3) ? 1.f : -1.f;
  u16 hbuf[32], lbuf[32];
#pragma unroll 8
  for (int k = 0; k < 32; ++k) {
    float v = Wa[(s * 32 + k) * 256 + n] + c1 * Wb[(s * 32 + k) * 256 + n];
    if (mat == 0) { hbuf[k] = bfh(v); lbuf[k] = bfh(v - bup(hbuf[k])); }
    else          { hbuf[k] = bfrn(v); }
  }
  u16* dh = ws + ((mat == 0) ? WH0o : (WRo + (size_t)(mat - 1) * 65536))
             + (size_t)s * 8192 + n * 32;
#pragma unroll
  for (int p = 0; p < 4; ++p) *(uint4*)(dh + p * 8) = ((const uint4*)hbuf)[p];
  if (mat == 0) {
    u16* dl = ws + WL0o + (size_t)s * 8192 + n * 32;
#pragma unroll
    for (int p = 0; p < 4; ++p) *(uint4*)(dl + p * 8) = ((const uint4*)lbuf)[p];
  }
}

// ---------------------------------------------------------------------------
// gzero: zero the +-64-col guards of the 3 S^T buffers (ws is 0xAA-poisoned).
// ---------------------------------------------------------------------------
__global__ __launch_bounds__(256) void gzero(u16* __restrict__ ws) {
  int g = blockIdx.x * 256 + threadIdx.x;          // 24576 threads
  int r = g >> 13, rem = g & 8191;
  int d = rem >> 5, p = rem & 31;
  size_t base = ST0 + (size_t)r * STMAT + (size_t)d * STROW;
  size_t off = (p < 16) ? (base + p * 4) : (base + 16448 + (p - 16) * 4);
  *(ushort4*)(ws + off) = make_ushort4(0, 0, 0, 0);
}

// ---------------------------------------------------------------------------
// gemmS: per mat, C tile 64 x 256 per block (512 thr, 8 waves; wave w owns
// cols [w*32, w*32+32)). mat0: split 3-MFMA -> yh/yl. mats1-3: single bf16
// MFMA -> S^T (transposed via padded LDS tile, stride 80 u16).
// ---------------------------------------------------------------------------
__global__ __launch_bounds__(512) void gemmS(u16* __restrict__ ws) {
  __shared__ __align__(16) u16 Ahs[2048], Als[2048];   // [64][32]
  __shared__ __align__(16) u16 BU[20480];   // union: Bh[8192]+Bl[8192] | Ct[256][80]

  const int t = threadIdx.x, mat = blockIdx.y, row0 = blockIdx.x * 64;
  const int w = t >> 6, ln = t & 15, quad = (t & 63) >> 4, q8 = quad * 8;
  const int n2base = w * 32;

  const u16* Wh = ws + ((mat == 0) ? WH0o : (WRo + (size_t)(mat - 1) * 65536));
  const u16* Wl = ws + WL0o;
  const u16* xh = ws + XHo;
  const u16* xl = ws + XLo;
  const u16* xr = ws + XRo;

  floatx4 acc[4][2];
#pragma unroll
  for (int m = 0; m < 4; ++m)
#pragma unroll
    for (int n2 = 0; n2 < 2; ++n2) acc[m][n2] = (floatx4){0.f, 0.f, 0.f, 0.f};

  for (int s = 0; s < 8; ++s) {
    // --- A staging: pure b128 copies ---
    if (mat == 0) {
      int c = t & 255, arow = c >> 2, apart = (c & 3) * 8;
      const u16* src = ((t < 256) ? xh : xl) + (size_t)(row0 + arow) * 256 + s * 32 + apart;
      u16* dst = ((t < 256) ? Ahs : Als) + arow * 32 + apart;
      *(uint4*)dst = *(const uint4*)src;
    } else if (t < 256) {
      int arow = t >> 2, apart = (t & 3) * 8;
      *(uint4*)(Ahs + arow * 32 + apart) =
          *(const uint4*)(xr + (size_t)(row0 + arow) * 256 + s * 32 + apart);
    }
    // --- B staging: linear image copy ---
    if (mat == 0) {
#pragma unroll
      for (int cc = 0; cc < 4; ++cc) {
        int c = t + 512 * cc;                       // 0..2047
        const u16* src = ((c < 1024) ? Wh : Wl) + (size_t)s * 8192 + (c & 1023) * 8;
        u16* dst = ((c < 1024) ? BU : BU + 8192) + (c & 1023) * 8;
        *(uint4*)dst = *(const uint4*)src;
      }
    } else {
#pragma unroll
      for (int cc = 0; cc < 2; ++cc) {
        int c = t + 512 * cc;                       // 0..1023
        *(uint4*)(BU + c * 8) = *(const uint4*)(Wh + (size_t)s * 8192 + c * 8);
      }
    }
    __syncthreads();

    short8 ah[4], al[4];
#pragma unroll
    for (int m = 0; m < 4; ++m) {
      ah[m] = *(const short8*)(Ahs + (m * 16 + ln) * 32 + q8);
      if (mat == 0) al[m] = *(const short8*)(Als + (m * 16 + ln) * 32 + q8);
    }
    short8 bh[2], bl[2];
#pragma unroll
    for (int n2 = 0; n2 < 2; ++n2) {
      int n = n2base + n2 * 16 + ln;
      bh[n2] = *(const short8*)(BU + n * 32 + q8);
      if (mat == 0) bl[n2] = *(const short8*)(BU + 8192 + n * 32 + q8);
    }
#pragma unroll
    for (int m = 0; m < 4; ++m)
#pragma unroll
      for (int n2 = 0; n2 < 2; ++n2) {
        acc[m][n2] = __builtin_amdgcn_mfma_f32_16x16x32_bf16(ah[m], bh[n2], acc[m][n2], 0, 0, 0);
        if (mat == 0) {
          acc[m][n2] = __builtin_amdgcn_mfma_f32_16x16x32_bf16(ah[m], bl[n2], acc[m][n2], 0, 0, 0);
          acc[m][n2] = __builtin_amdgcn_mfma_f32_16x16x32_bf16(al[m], bh[n2], acc[m][n2], 0, 0, 0);
        }
      }
    __syncthreads();
  }

  if (mat == 0) {
    // y split epilogue: yh/yl [j][d]
#pragma unroll
    for (int m = 0; m < 4; ++m)
#pragma unroll
      for (int n2 = 0; n2 < 2; ++n2) {
        int col = n2base + n2 * 16 + ln;
#pragma unroll
        for (int r = 0; r < 4; ++r) {
          int row = row0 + m * 16 + quad * 4 + r;
          float y = acc[m][n2][r];
          u16 hh = bfh(y);
          ws[YHo + (size_t)row * 256 + col] = hh;
          ws[YLo + (size_t)row * 256 + col] = bfh(y - bup(hh));
        }
      }
  } else {
    // transposed bf16 epilogue via LDS Ct[256 d][80 pad], rows are m-contig
#pragma unroll
    for (int m = 0; m < 4; ++m)
#pragma unroll
      for (int n2 = 0; n2 < 2; ++n2) {
        int col = n2base + n2 * 16 + ln;
        ushort4 pk = make_ushort4(bfrn(acc[m][n2][0]), bfrn(acc[m][n2][1]),
                                  bfrn(acc[m][n2][2]), bfrn(acc[m][n2][3]));
        *(ushort4*)(BU + col * 80 + m * 16 + quad * 4) = pk;
      }
    __syncthreads();
    u16* STm = ws + ST0 + (size_t)(mat - 1) * STMAT;
#pragma unroll
    for (int cc = 0; cc < 4; ++cc) {
      int c = t + 512 * cc;                          // 0..2047
      int d = c >> 3, part = c & 7;
      *(uint4*)(STm + (size_t)d * STROW + 64 + row0 + part * 8) =
          *(const uint4*)(BU + d * 80 + part * 8);
    }
  }
}

// ---------------------------------------------------------------------------
// fused_attn: 64 utterances/block, 512 thr. Phase 1: P = Y.X^T (split bf16,
// pre-split operands). Softmax in LDS. Phase 2: H = Ap@S1 + Asm@S2 + Af@S3
// (bf16 MFMA, S^T linear staging). Cross-wave log_softmax epilogue.
// ---------------------------------------------------------------------------
__global__ __launch_bounds__(512) void fused_attn(
    const u16* __restrict__ ws, const int* __restrict__ spk,
    float* __restrict__ out)
{
  __shared__ float Plds[64][196];
  __shared__ __align__(16) u16 stg[30720];   // ph1: Xh|Xl|Yh|Yl  ph2: Sl|Ac
  __shared__ int spkw[192];
  __shared__ float pmax[64][8], psum[64][8], gmaxs[64], glse[64];

  const int t    = threadIdx.x;
  const int w    = t >> 6;
  const int ln   = t & 15;
  const int quad = (t & 63) >> 4;
  const int q8   = quad * 8;
  const int i0   = blockIdx.x * 64;

  if (t < 192) {
    int j = i0 + t - 64;
    spkw[t] = spk[min(max(j, 0), NU - 1)];
  }

  // ---------------- Phase 1: logits GEMM (pre-split copies) ----------------
  floatx4 accP[6];
#pragma unroll
  for (int cc = 0; cc < 6; ++cc) accP[cc] = (floatx4){0.f, 0.f, 0.f, 0.f};
  const int m0  = (w >> 1) * 16;
  const int ct0 = (w & 1) * 6;

  for (int kd = 0; kd < DIM; kd += 32) {
#pragma unroll
    for (int cc = 0; cc < 4; ++cc) {
      int c = t + 512 * cc;                         // 0..2047
      if (c < 1536) {                               // X window: 192 rows
        int row = c >> 3, sub = c & 7, hil = sub >> 2, part = sub & 3;
        int jc = min(max(i0 + row - 64, 0), NU - 1);
        const u16* src = ws + (hil ? XLo : XHo) + (size_t)jc * 256 + kd + part * 8;
        *(uint4*)(stg + (hil ? 6144 : 0) + row * 32 + part * 8) = *(const uint4*)src;
      } else {                                      // Y: 64 rows
        int c2 = c - 1536;
        int row = c2 >> 3, sub = c2 & 7, hil = sub >> 2, part = sub & 3;
        const u16* src = ws + (hil ? YLo : YHo) + (size_t)(i0 + row) * 256 + kd + part * 8;
        *(uint4*)(stg + 12288 + (hil ? 2048 : 0) + row * 32 + part * 8) = *(const uint4*)src;
      }
    }
    __syncthreads();

    short8 ah = *(const short8*)(stg + 12288 + (m0 + ln) * 32 + q8);
    short8 al = *(const short8*)(stg + 14336 + (m0 + ln) * 32 + q8);
#pragma unroll
    for (int cc = 0; cc < 6; ++cc) {
      int xrow = (ct0 + cc) * 16 + ln;
      short8 bh = *(const short8*)(stg + xrow * 32 + q8);
      short8 bl = *(const short8*)(stg + 6144 + xrow * 32 + q8);
      accP[cc] = __builtin_amdgcn_mfma_f32_16x16x32_bf16(ah, bh, accP[cc], 0, 0, 0);
      accP[cc] = __builtin_amdgcn_mfma_f32_16x16x32_bf16(ah, bl, accP[cc], 0, 0, 0);
      accP[cc] = __builtin_amdgcn_mfma_f32_16x16x32_bf16(al, bh, accP[cc], 0, 0, 0);
    }
    __syncthreads();
  }
#pragma unroll
  for (int cc = 0; cc < 6; ++cc)
#pragma unroll
    for (int r = 0; r < 4; ++r)
      Plds[m0 + quad * 4 + r][(ct0 + cc) * 16 + ln] = accP[cc][r];
  __syncthreads();

  // ---------------- Softmax over each row's 128-slot band ----------------
  {
    int row = t >> 3, s = t & 7;
    float vals[16];
    float mx = -3.4e38f;
#pragma unroll
    for (int q = 0; q < 16; ++q) {
      int c = row + s * 16 + q;
      int j = i0 + c - 64;
      float pv = ((j >= 0) && (j < NU)) ? Plds[row][c] : 0.f;
      vals[q] = pv;
      mx = fmaxf(mx, pv);
    }
#pragma unroll
    for (int o = 1; o < 8; o <<= 1) mx = fmaxf(mx, __shfl_xor(mx, o));
    float sm = 0.f;
#pragma unroll
    for (int q = 0; q < 16; ++q) { vals[q] = __expf(vals[q] - mx); sm += vals[q]; }
#pragma unroll
    for (int o = 1; o < 8; o <<= 1) sm += __shfl_xor(sm, o);
    float inv = 1.f / sm;
#pragma unroll
    for (int q = 0; q < 16; ++q) {
      int c = row + s * 16 + q;
      int j = i0 + c - 64;
      Plds[row][c] = ((j >= 0) && (j < NU)) ? vals[q] * inv : 0.f;
    }
#pragma unroll
    for (int q = 0; q < 8; ++q) {                 // zero out-of-band slots
      int c2 = row + 128 + s * 8 + q;
      if (c2 >= 192) c2 -= 192;
      Plds[row][c2] = 0.f;
    }
  }
  __syncthreads();

  // ---------------- Phase 2: aggregation GEMMs ----------------
  const int n0 = w * 32;
  floatx4 acc2[4][2];
#pragma unroll
  for (int m = 0; m < 4; ++m)
#pragma unroll
    for (int n2 = 0; n2 < 2; ++n2) acc2[m][n2] = (floatx4){0.f, 0.f, 0.f, 0.f};

  for (int kj = 0; kj < 192; kj += 32) {
    const int jcol = i0 + kj;                      // S^T col = 64 + jbase
    // S^T staging: 3 x 256 rows x 64 B, linear
#pragma unroll
    for (int cc = 0; cc < 6; ++cc) {
      int c = t + 512 * cc;                        // 0..3071
      int r = c >> 10, d = (c >> 2) & 255, part = c & 3;
      const u16* src = ws + ST0 + (size_t)r * STMAT + (size_t)d * STROW + jcol + part * 8;
      *(uint4*)(stg + r * 8192 + d * 32 + part * 8) = *(const uint4*)src;
    }
    // masked attn chunks: Ac[0]=pred, Ac[1]=same, Ac[2]=full
    {
      int row = t >> 3, cg = t & 7, cb = kj + cg * 4;
      float4 av = *(const float4*)(&Plds[row][cb]);
      float aa[4] = {av.x, av.y, av.z, av.w};
      int sr = spkw[row + 64];
      u16 b0[4], b1[4], b2[4];
#pragma unroll
      for (int q = 0; q < 4; ++q) {
        int c = cb + q;
        u16 ab = bfrn(aa[q]);
        b0[q] = (c - row >= 64) ? ab : (u16)0;
        b1[q] = (spkw[c] == sr) ? ab : (u16)0;
        b2[q] = ab;
      }
      *(ushort4*)(stg + 24576 + row * 32 + cg * 4) = make_ushort4(b0[0], b0[1], b0[2], b0[3]);
      *(ushort4*)(stg + 26624 + row * 32 + cg * 4) = make_ushort4(b1[0], b1[1], b1[2], b1[3]);
      *(ushort4*)(stg + 28672 + row * 32 + cg * 4) = make_ushort4(b2[0], b2[1], b2[2], b2[3]);
    }
    __syncthreads();

    short8 af[3][4], bfv[3][2];
#pragma unroll
    for (int r = 0; r < 3; ++r) {
#pragma unroll
      for (int m = 0; m < 4; ++m)
        af[r][m] = *(const short8*)(stg + 24576 + r * 2048 + (m * 16 + ln) * 32 + q8);
#pragma unroll
      for (int n2 = 0; n2 < 2; ++n2) {
        int d = n0 + n2 * 16 + ln;
        bfv[r][n2] = *(const short8*)(stg + r * 8192 + d * 32 + q8);
      }
    }
#pragma unroll
    for (int r = 0; r < 3; ++r)
#pragma unroll
      for (int m = 0; m < 4; ++m)
#pragma unroll
        for (int n2 = 0; n2 < 2; ++n2)
          acc2[m][n2] = __builtin_amdgcn_mfma_f32_16x16x32_bf16(
              af[r][m], bfv[r][n2], acc2[m][n2], 0, 0, 0);
    __syncthreads();
  }

  // ---------------- log_softmax over 256 dims (cross-wave) ----------------
#pragma unroll
  for (int m = 0; m < 4; ++m)
#pragma unroll
    for (int r = 0; r < 4; ++r) {
      float v = fmaxf(acc2[m][0][r], acc2[m][1][r]);
#pragma unroll
      for (int o = 1; o < 16; o <<= 1) v = fmaxf(v, __shfl_xor(v, o));
      if (ln == 0) pmax[m * 16 + quad * 4 + r][w] = v;
    }
  __syncthreads();
  if (t < 64) {
    float g = pmax[t][0];
#pragma unroll
    for (int ww = 1; ww < 8; ++ww) g = fmaxf(g, pmax[t][ww]);
    gmaxs[t] = g;
  }
  __syncthreads();
#pragma unroll
  for (int m = 0; m < 4; ++m)
#pragma unroll
    for (int r = 0; r < 4; ++r) {
      float g = gmaxs[m * 16 + quad * 4 + r];
      float e = __expf(acc2[m][0][r] - g) + __expf(acc2[m][1][r] - g);
#pragma unroll
      for (int o = 1; o < 16; o <<= 1) e += __shfl_xor(e, o);
      if (ln == 0) psum[m * 16 + quad * 4 + r][w] = e;
    }
  __syncthreads();
  if (t < 64) {
    float s = psum[t][0];
#pragma unroll
    for (int ww = 1; ww < 8; ++ww) s += psum[t][ww];
    glse[t] = gmaxs[t] + logf(s);
  }
  __syncthreads();

#pragma unroll
  for (int m = 0; m < 4; ++m) {
    int rl0 = m * 16 + quad * 4;
#pragma unroll
    for (int r = 0; r < 4; ++r) {
      float l = glse[rl0 + r];
      size_t rowg = (size_t)(i0 + rl0 + r) * DIM;
      out[rowg + n0 + ln]      = acc2[m][0][r] - l;
      out[rowg + n0 + 16 + ln] = acc2[m][1][r] - l;
    }
  }
}

extern "C" void kernel_launch(void* const* d_in, const int* in_sizes, int n_in,
                              void* d_out, int out_size, void* d_ws, size_t ws_size,
                              hipStream_t stream) {
  const float* x   = (const float*)d_in[0];
  const int*   spk = (const int*)d_in[1];
  const float* wat = (const float*)d_in[2];
  const float* wpr = (const float*)d_in[3];
  const float* wsu = (const float*)d_in[4];
  const float* wsm = (const float*)d_in[5];
  const float* wdf = (const float*)d_in[6];
  float* out = (float*)d_out;
  u16* ws = (u16*)d_ws;    // ~68 MB used

  hipLaunchKernelGGL(xprep, dim3(4096), dim3(256), 0, stream, x, ws);
  hipLaunchKernelGGL(wprep, dim3(8, 4), dim3(256), 0, stream,
                     wat, wpr, wsu, wsm, wdf, ws);
  hipLaunchKernelGGL(gzero, dim3(96), dim3(256), 0, stream, ws);
  hipLaunchKernelGGL(gemmS, dim3(256, 4), dim3(512), 0, stream, ws);
  hipLaunchKernelGGL(fused_attn, dim3(256), dim3(512), 0, stream, ws, spk, out);
}